// Round 8
// baseline (1517.645 us; speedup 1.0000x reference)
//
#include <hip/hip_runtime.h>
#include <hip/hip_bf16.h>

#define HID 64
#define INDIM 128
#define BK_SHIFT 7            // 128 nodes per bucket
#define BK_NODES 128
#define NBK_MAX 1024          // supports N <= 131072
#define PB_BLOCKS 1024
#define PB_MAXI 8             // supports E <= 1024*256*8 = 2.097M
#define AST 68                // LDS acc row stride (f32 words): 68%32=4 -> bank rotation

typedef __attribute__((ext_vector_type(8))) short bf16x8;
typedef __attribute__((ext_vector_type(4))) float f32x4;

static __device__ __forceinline__ short f2bf(float f) {
    __hip_bfloat16 h = __float2bfloat16(f);
    return *reinterpret_cast<short*>(&h);
}
static __device__ __forceinline__ float bf2f(short s) {
    return __uint_as_float(((unsigned)(unsigned short)s) << 16);
}

// ---------- CSR build: fixed-capacity buckets (R5 bpart, verbatim) ----------
// R4 lesson: per-edge global atomics on node-granular arrays cost ~+50us.
// R6 lesson: random 4B scatter writes pay 16x line amplification (96MB for 6.4MB).
// bpart avoids both: LDS histogram + per-block contiguous chunk claims per bucket.

__global__ __launch_bounds__(256) void bpart_k(const int* __restrict__ src,
                                               const int* __restrict__ dst,
                                               int* __restrict__ cursor,
                                               int* __restrict__ bucketed, int E, int cap) {
    __shared__ int hist[NBK_MAX];
    __shared__ int base[NBK_MAX];
    for (int i = threadIdx.x; i < NBK_MAX; i += 256) hist[i] = 0;
    __syncthreads();
    int code[PB_MAXI];
#pragma unroll
    for (int i = 0; i < PB_MAXI; i++) {
        code[i] = -1;
        long e = (long)i * (PB_BLOCKS * 256) + (long)blockIdx.x * 256 + threadIdx.x;
        if (e < E) {
            int b = dst[e] >> BK_SHIFT;
            int p = atomicAdd(&hist[b], 1);   // p < 2048 (block edge total)
            code[i] = (b << 12) | p;
        }
    }
    __syncthreads();
    for (int i = threadIdx.x; i < NBK_MAX; i += 256)
        base[i] = hist[i] ? (i * cap + atomicAdd(&cursor[i], hist[i])) : 0;
    __syncthreads();
#pragma unroll
    for (int i = 0; i < PB_MAXI; i++) {
        long e = (long)i * (PB_BLOCKS * 256) + (long)blockIdx.x * 256 + threadIdx.x;
        if (e < E) {
            int b = code[i] >> 12, p = code[i] & 0xFFF;
            int pos = base[b] + p;
            if (pos < (b + 1) * cap)          // overflow guard (never hit for random dst)
                bucketed[pos] = src[e] | ((dst[e] & (BK_NODES - 1)) << 20);
        }
    }
}

// build the hi/lo bf16 B-fragment planes for a 64x64 weight into global workspace:
// slot sid holds B[kb..kb+7][col]; plane H at [0,512), plane L at [512,1024) slots.
static __device__ __forceinline__ void wfrag_body(const float* __restrict__ Wsrc,
                                                  short* __restrict__ out) {
    int t = threadIdx.x;
#pragma unroll
    for (int s = 0; s < 2; s++) {
        int sid = t + s * 256;
        int col = (((sid >> 6) & 3) << 4) + (sid & 15);
        int kb  = ((sid >> 8) << 5) + (((sid >> 4) & 3) << 3);
        union { short s[8]; uint4 u; } ph, pl;
#pragma unroll
        for (int i = 0; i < 8; i++) {
            float w = Wsrc[(kb + i) * 64 + col];
            short h = f2bf(w);
            ph.s[i] = h;
            pl.s[i] = f2bf(w - bf2f(h));
        }
        ((uint4*)out)[sid] = ph.u;
        ((uint4*)out)[512 + sid] = pl.u;
    }
}

// Replaces the full counting sort (R5 bsort, 38us): fgacc_k consumes UNSORTED bucket
// entries, so only per-node degree is needed. Blocks [0,nb): LDS histogram over the
// bucket's entries -> dinv. Blocks nb, nb+1: W2/Wfc fragment-plane builders.
__global__ __launch_bounds__(256) void degcnt_k(const int* __restrict__ bucketed,
                                                const int* __restrict__ cursor,
                                                float* __restrict__ dinv, int N, int cap,
                                                int nb,
                                                const float* __restrict__ W2,
                                                const float* __restrict__ Wfc,
                                                short* __restrict__ wf2,
                                                short* __restrict__ wffc) {
    __shared__ int deg[BK_NODES];
    int b = blockIdx.x, t = threadIdx.x;
    if (b >= nb) {
        wfrag_body(b == nb ? W2 : Wfc, b == nb ? wf2 : wffc);
        return;
    }
    if (t < BK_NODES) deg[t] = 0;
    __syncthreads();
    int estart = b * cap;
    int ecnt = cursor[b];
    for (int j = t; j < ecnt; j += 256)
        atomicAdd(&deg[bucketed[estart + j] >> 20], 1);
    __syncthreads();
    int nstart = b << BK_SHIFT;
    if (t < BK_NODES && nstart + t < N)
        dinv[nstart + t] = rsqrtf(1.0f + (float)deg[t]);  // self-loop + in-degree
}

// ---------- compute ----------

// hs1[M,64] = ((x[M,128] @ W1) * dinv) in bf16, via MFMA with hi/lo bf16 split (R5).
__global__ __launch_bounds__(256) void gemm1_k(const float* __restrict__ A,
                                               const float* __restrict__ W,
                                               const float* __restrict__ dinv,
                                               __hip_bfloat16* __restrict__ C, int M) {
    __shared__ __align__(16) short WH[1024 * 8];   // 16KB: [(kt*4+nt)*64 + lane][8]
    __shared__ __align__(16) short WL[1024 * 8];   // 16KB
    int t = threadIdx.x;
    int lane = t & 63;
    int wid = t >> 6;
    int q = lane & 15, g = lane >> 4;
    int tile = blockIdx.x << 6;

#pragma unroll
    for (int s = 0; s < 4; s++) {
        int sid = t + s * 256;
        int col = (((sid >> 6) & 3) << 4) + (sid & 15);
        int kb  = ((sid >> 8) << 5) + (((sid >> 4) & 3) << 3);
        union { short s[8]; uint4 u; } ph, pl;
#pragma unroll
        for (int i = 0; i < 8; i++) {
            float w = W[(kb + i) * HID + col];
            short h = f2bf(w);
            ph.s[i] = h;
            pl.s[i] = f2bf(w - bf2f(h));
        }
        *((uint4*)WH + sid) = ph.u;
        *((uint4*)WL + sid) = pl.u;
    }
    __syncthreads();

    int arow = tile + (wid << 4) + q;
    if (arow >= M) arow = M - 1;              // clamped rows discarded at store
    const float* ap = A + (long)arow * INDIM + (g << 3);
    f32x4 acc[4] = {};
#pragma unroll
    for (int kt = 0; kt < 4; kt++) {
        float4 x0 = *(const float4*)(ap + (kt << 5));
        float4 x1 = *(const float4*)(ap + (kt << 5) + 4);
        float xv[8] = {x0.x, x0.y, x0.z, x0.w, x1.x, x1.y, x1.z, x1.w};
        union { short s[8]; bf16x8 v; } ah, al;
#pragma unroll
        for (int i = 0; i < 8; i++) {
            short h = f2bf(xv[i]);
            ah.s[i] = h;
            al.s[i] = f2bf(xv[i] - bf2f(h));
        }
#pragma unroll
        for (int nt = 0; nt < 4; nt++) {
            int soff = ((((kt << 2) + nt) << 6) + lane) << 4;
            bf16x8 bh = *(const bf16x8*)((const char*)WH + soff);
            bf16x8 bl = *(const bf16x8*)((const char*)WL + soff);
            acc[nt] = __builtin_amdgcn_mfma_f32_16x16x32_bf16(ah.v, bh, acc[nt], 0, 0, 0);
            acc[nt] = __builtin_amdgcn_mfma_f32_16x16x32_bf16(ah.v, bl, acc[nt], 0, 0, 0);
            acc[nt] = __builtin_amdgcn_mfma_f32_16x16x32_bf16(al.v, bh, acc[nt], 0, 0, 0);
        }
    }
    // C/D layout: col = (nt<<4)+q, row = (g<<2)+reg. Scale by dinv, store bf16.
    int rbase = tile + (wid << 4) + (g << 2);
#pragma unroll
    for (int reg = 0; reg < 4; reg++) {
        int node = rbase + reg;
        if (node < M) {
            float di = dinv[node];
            __hip_bfloat16* out = C + ((long)node << 6) + q;
#pragma unroll
            for (int nt = 0; nt < 4; nt++)
                out[nt << 4] = __float2bfloat16(acc[nt][reg] * di);
        }
    }
}

#define LO16(u) __uint_as_float((u) << 16)
#define HI16(u) __uint_as_float((u) & 0xffff0000u)
#define ATOMIC8(ap, v)                                                        \
    do {                                                                      \
        atomicAdd((ap) + 0, LO16((v).x)); atomicAdd((ap) + 1, HI16((v).x));   \
        atomicAdd((ap) + 2, LO16((v).y)); atomicAdd((ap) + 3, HI16((v).y));   \
        atomicAdd((ap) + 4, LO16((v).z)); atomicAdd((ap) + 5, HI16((v).z));   \
        atomicAdd((ap) + 6, LO16((v).w)); atomicAdd((ap) + 7, HI16((v).w));   \
    } while (0)

// fused gather + GCN epilogue via LDS f32 atomic accumulation. Block = 128-node bucket.
//  init:   acc[row][*] = hs[self] (edge-sum accumulates on top), 0 for OOB rows.
//  stream: UNSORTED bucketed entries, sequential+coalesced. Each edge: 8 lanes x
//          uint4 gather of hs[src] -> 8 ds_add_f32 into acc[ldst]. NO per-node
//          chains: every gather in the block is independent (vs 8 serial rounds +
//          idx->gather chains in the old per-node fgather). 4 edges/octet pipelined.
//  FC:     barrier once; A-frags read straight from acc (relu/bias/hi-lo split in
//          registers); B-frags from global wf (L1). 48 MFMA/wave, 2 row-tiles.
// LDS = 128*AST*4 = 34KB -> 4 blocks/CU. f32 atomic reorder noise ~1e-7 rel << bf16 2^-9.
template <bool HS_OUT>
__global__ __launch_bounds__(256) void fgacc_k(void* __restrict__ outp,
                                               const __hip_bfloat16* __restrict__ hs,
                                               const float* __restrict__ dinv,
                                               const float* __restrict__ biasA,
                                               const short* __restrict__ wf,
                                               const float* __restrict__ biasB,
                                               const int* __restrict__ cursor,
                                               const int* __restrict__ bucketed,
                                               int N, int cap) {
    __shared__ __align__(16) float acc[BK_NODES * AST];

    int t = threadIdx.x;
    int b = blockIdx.x;
    int nstart = b << BK_SHIFT;
    int ncnt = min(BK_NODES, N - nstart);
    int estart = b * cap;
    int ecnt = cursor[b];
    int f8 = t & 7, f0 = f8 << 3;             // feature octet
    int oc = t >> 3;                          // edge-slot 0..31

    // ---- init: self-loop row (or 0 for OOB rows) ----
#pragma unroll
    for (int rr = 0; rr < 4; rr++) {
        int row = (rr << 5) + oc;
        float v[8] = {0.f, 0.f, 0.f, 0.f, 0.f, 0.f, 0.f, 0.f};
        if (row < ncnt) {
            uint4 hv = *(const uint4*)(hs + (((nstart + row) << 6) + f0));
            v[0] = LO16(hv.x); v[1] = HI16(hv.x); v[2] = LO16(hv.y); v[3] = HI16(hv.y);
            v[4] = LO16(hv.z); v[5] = HI16(hv.z); v[6] = LO16(hv.w); v[7] = HI16(hv.w);
        }
        float* ap = acc + row * AST + f0;     // row*AST*4 = 272B, 16B-aligned
        *(float4*)ap       = make_float4(v[0], v[1], v[2], v[3]);
        *(float4*)(ap + 4) = make_float4(v[4], v[5], v[6], v[7]);
    }
    __syncthreads();

    // ---- stream edges: 128/iter (4 per octet), entries prefetched one iter ahead ----
    if (ecnt > 0) {
        int jmax = ecnt - 1;
        const int* bk = bucketed + estart;
        int ea = bk[min(oc, jmax)];
        int eb = bk[min(oc + 32, jmax)];
        int ec = bk[min(oc + 64, jmax)];
        int ed = bk[min(oc + 96, jmax)];
        for (int j = oc; j < ecnt; j += 128) {
            uint4 ha = *(const uint4*)(hs + (((ea & 0xFFFFF) << 6) + f0));
            uint4 hb = *(const uint4*)(hs + (((eb & 0xFFFFF) << 6) + f0));
            uint4 hc = *(const uint4*)(hs + (((ec & 0xFFFFF) << 6) + f0));
            uint4 hd = *(const uint4*)(hs + (((ed & 0xFFFFF) << 6) + f0));
            int la = ea >> 20, lb = eb >> 20, lc = ec >> 20, ldd = ed >> 20;
            bool vb = j + 32 < ecnt, vc = j + 64 < ecnt, vd = j + 96 < ecnt;
            int jn = j + 128;                 // prefetch next iteration's entries
            ea = bk[min(jn, jmax)];
            eb = bk[min(jn + 32, jmax)];
            ec = bk[min(jn + 64, jmax)];
            ed = bk[min(jn + 96, jmax)];
            { float* ap = acc + la * AST + f0; ATOMIC8(ap, ha); }   // j < ecnt by loop cond
            if (vb) { float* ap = acc + lb * AST + f0; ATOMIC8(ap, hb); }
            if (vc) { float* ap = acc + lc * AST + f0; ATOMIC8(ap, hc); }
            if (vd) { float* ap = acc + ldd * AST + f0; ATOMIC8(ap, hd); }
        }
    }
    __syncthreads();

    // ---- FC via MFMA, A-frags straight from acc, B-frags from global (L1) ----
    int lane = t & 63;
    int wid = __builtin_amdgcn_readfirstlane(t >> 6);
    int q = lane & 15, g = lane >> 4;
    const bf16x8* wfv = (const bf16x8*)wf;
    f32x4 cacc[2][4] = {};
#pragma unroll
    for (int rt = 0; rt < 2; rt++) {
        int row = (wid << 5) + (rt << 4) + q;
        float di = (row < ncnt) ? dinv[nstart + row] : 0.0f;
#pragma unroll
        for (int kt = 0; kt < 2; kt++) {
            const float* ap = acc + row * AST + (kt << 5) + (g << 3);
            float4 u0 = *(const float4*)(ap);
            float4 u1 = *(const float4*)(ap + 4);
            float4 b0 = *(const float4*)(biasA + (kt << 5) + (g << 3));
            float4 b1 = *(const float4*)(biasA + (kt << 5) + (g << 3) + 4);
            float rv[8] = {
                fmaxf(fmaf(di, u0.x, b0.x), 0.f), fmaxf(fmaf(di, u0.y, b0.y), 0.f),
                fmaxf(fmaf(di, u0.z, b0.z), 0.f), fmaxf(fmaf(di, u0.w, b0.w), 0.f),
                fmaxf(fmaf(di, u1.x, b1.x), 0.f), fmaxf(fmaf(di, u1.y, b1.y), 0.f),
                fmaxf(fmaf(di, u1.z, b1.z), 0.f), fmaxf(fmaf(di, u1.w, b1.w), 0.f)};
            union { short s[8]; bf16x8 v; } ah, al;
#pragma unroll
            for (int i = 0; i < 8; i++) {
                short h = f2bf(rv[i]);
                ah.s[i] = h;
                al.s[i] = f2bf(rv[i] - bf2f(h));
            }
#pragma unroll
            for (int nt = 0; nt < 4; nt++) {
                int sid = (((kt << 2) + nt) << 6) + lane;
                bf16x8 bh = wfv[sid];
                bf16x8 bl = wfv[512 + sid];
                cacc[rt][nt] = __builtin_amdgcn_mfma_f32_16x16x32_bf16(ah.v, bh, cacc[rt][nt], 0, 0, 0);
                cacc[rt][nt] = __builtin_amdgcn_mfma_f32_16x16x32_bf16(ah.v, bl, cacc[rt][nt], 0, 0, 0);
                cacc[rt][nt] = __builtin_amdgcn_mfma_f32_16x16x32_bf16(al.v, bh, cacc[rt][nt], 0, 0, 0);
            }
        }
    }

    // ---- epilogue: C[row = (g<<2)+reg][col = (nt<<4)+q] per 16-row tile ----
    int rb = wid << 5;
    if (HS_OUT) {
        __hip_bfloat16* out = (__hip_bfloat16*)outp;
#pragma unroll
        for (int rt = 0; rt < 2; rt++)
#pragma unroll
            for (int reg = 0; reg < 4; reg++) {
                int row = rb + (rt << 4) + (g << 2) + reg;
                if (row < ncnt) {
                    int node = nstart + row;
                    float di = dinv[node];
#pragma unroll
                    for (int nt = 0; nt < 4; nt++)
                        out[(node << 6) + (nt << 4) + q] =
                            __float2bfloat16(cacc[rt][nt][reg] * di);
                }
            }
    } else {
        float* out = (float*)outp;
        float bB[4];
#pragma unroll
        for (int nt = 0; nt < 4; nt++) bB[nt] = biasB[(nt << 4) + q];
#pragma unroll
        for (int rt = 0; rt < 2; rt++)
#pragma unroll
            for (int reg = 0; reg < 4; reg++) {
                int row = rb + (rt << 4) + (g << 2) + reg;
                if (row < ncnt) {
                    int node = nstart + row;
#pragma unroll
                    for (int nt = 0; nt < 4; nt++)
                        out[(node << 6) + (nt << 4) + q] = cacc[rt][nt][reg] + bB[nt];
                }
            }
    }
}

extern "C" void kernel_launch(void* const* d_in, const int* in_sizes, int n_in,
                              void* d_out, int out_size, void* d_ws, size_t ws_size,
                              hipStream_t stream) {
    const float* x   = (const float*)d_in[0];
    const int*   ei  = (const int*)d_in[1];
    const float* W1  = (const float*)d_in[2];
    const float* b1  = (const float*)d_in[3];
    const float* W2  = (const float*)d_in[4];
    const float* b2  = (const float*)d_in[5];
    const float* Wfc = (const float*)d_in[6];
    const float* bfc = (const float*)d_in[7];

    int N = in_sizes[0] / INDIM;
    int E = in_sizes[1] / 2;
    const int* src = ei;       // edge_index row 0
    const int* dst = ei + E;   // edge_index row 1
    int nb = (N + BK_NODES - 1) >> BK_SHIFT;          // 782 buckets
    int cap = (2 * E / nb + 63) & ~63;                // 2x mean bucket load
    if (cap < 4096) cap = 4096;

    char* ws = (char*)d_ws;
    auto alloc = [&](size_t bytes) {
        char* p = ws;
        ws += (bytes + 15) & ~(size_t)15;
        return p;
    };
    float* dinv     = (float*)alloc(sizeof(float) * (size_t)N);
    int*   cursor   = (int*)alloc(sizeof(int) * NBK_MAX);
    int*   bucketed = (int*)alloc(sizeof(int) * (size_t)nb * cap);  // lives through both fgacc
    short* wf2      = (short*)alloc(sizeof(short) * 1024 * 8);      // 16KB frag planes
    short* wffc     = (short*)alloc(sizeof(short) * 1024 * 8);
    __hip_bfloat16* hs2 = (__hip_bfloat16*)alloc(sizeof(__hip_bfloat16) * (size_t)N * HID);
    // hs1 lives in d_out (25.6MB f32 region; hs1 needs 12.8MB bf16). Dead before
    // fgacc<false> overwrites d_out with the final f32 output.
    __hip_bfloat16* hs1 = (__hip_bfloat16*)d_out;
    float* outp     = (float*)d_out;

    hipMemsetAsync(cursor, 0, sizeof(int) * NBK_MAX, stream);

    bpart_k<<<PB_BLOCKS, 256, 0, stream>>>(src, dst, cursor, bucketed, E, cap);
    degcnt_k<<<nb + 2, 256, 0, stream>>>(bucketed, cursor, dinv, N, cap, nb,
                                         W2, Wfc, wf2, wffc);
    gemm1_k<<<(N + 63) / 64, 256, 0, stream>>>(x, W1, dinv, hs1, N);
    fgacc_k<true><<<nb, 256, 0, stream>>>(hs2, hs1, dinv, b1, wf2, nullptr,
                                          cursor, bucketed, N, cap);
    fgacc_k<false><<<nb, 256, 0, stream>>>(outp, hs2, dinv, b2, wffc, bfc,
                                           cursor, bucketed, N, cap);
}